// Round 2
// baseline (1188.545 us; speedup 1.0000x reference)
//
#include <hip/hip_runtime.h>

#define NN 4096
#define BB 128
#define GG 32          // NN / BB
#define MAXT 8
#define MAXE (MAXT * GG)

// ---------------------------------------------------------------------------
// Kernel 1: zero flags + parallel partial matvec  a_partial = W @ x
// 256 WGs: task (tm, tc) = (bid>>3, bid&7): rows [tm*128, +128), cols [tc*512, +512)
// ---------------------------------------------------------------------------
__global__ __launch_bounds__(256)
void hop_init(const float* __restrict__ x, const float* __restrict__ W,
              int* __restrict__ flags, float* __restrict__ partial_buf)
{
    const int tid = threadIdx.x, bid = blockIdx.x;
    const int lane = tid & 63, w = tid >> 6;
    const int lam = lane & 31, half = lane >> 5;

    if (bid == 0 && tid < MAXE) flags[tid] = 0;

    const int tm = bid >> 3, tc = bid & 7;
    const int rbase = tm * BB, cbase = tc * 512;

    float4 xv[4];
#pragma unroll
    for (int u = 0; u < 4; ++u)
        xv[u] = *(const float4*)(x + cbase + 4 * lam + 128 * u);

#pragma unroll 2
    for (int it = 0; it < 16; ++it) {
        const int r = w * 32 + it * 2 + half;
        const float* wrow = W + (size_t)(rbase + r) * NN + cbase;
        float p = 0.f;
#pragma unroll
        for (int u = 0; u < 4; ++u) {
            float4 wv = *(const float4*)(wrow + 4 * lam + 128 * u);
            p = fmaf(wv.x, xv[u].x, p); p = fmaf(wv.y, xv[u].y, p);
            p = fmaf(wv.z, xv[u].z, p); p = fmaf(wv.w, xv[u].w, p);
        }
#pragma unroll
        for (int s = 16; s; s >>= 1) p += __shfl_xor(p, s);
        if (lam == 0) partial_buf[(size_t)bid * BB + r] = p;
    }
}

// ---------------------------------------------------------------------------
// Kernel 2: 32 owner WGs, flag-pipelined blocked asynchronous sweeps
// ---------------------------------------------------------------------------
__global__ __launch_bounds__(256)
void hop_main(const float* __restrict__ x, const float* __restrict__ W,
              const int* __restrict__ maxit, float* __restrict__ out,
              int* __restrict__ flags, float* __restrict__ delta_buf,
              const float* __restrict__ partial_buf)
{
    __shared__ float wdT[BB][BB + 1];   // transposed diagonal tile, pad -> stride 129
    __shared__ float a_lds[BB];         // running activations of my block
    __shared__ float delta_lds[BB];
    __shared__ int   status_lds;

    const int tid = threadIdx.x;
    const int m = blockIdx.x;
    const int lane = tid & 63, w = tid >> 6;
    const int lam = lane & 31, half = lane >> 5;
    const int bm = m * BB;

    int T = *maxit; if (T > MAXT) T = MAXT; if (T < 0) T = 0;
    const long long tstart = clock64();

    // stage transposed diagonal tile (coalesced read, conflict-free write)
    for (int l = tid; l < BB * BB; l += 256) {
        const int i = l >> 7, j = l & 127;
        wdT[j][i] = W[(size_t)(bm + i) * NN + bm + j];
    }
    // gather init matvec partials
    if (tid < BB) {
        float s = 0.f;
#pragma unroll
        for (int c = 0; c < 8; ++c) s += partial_buf[(size_t)(m * 8 + c) * BB + tid];
        a_lds[tid] = s;
    }
    float sold0 = 0.f, sold1 = 0.f;
    if (w == 0) { sold0 = x[bm + lane]; sold1 = x[bm + 64 + lane]; }
    __syncthreads();

    for (int e = 0; e < T * GG; ++e) {
        const int k = e & (GG - 1);
        if (k != m) {
            // ---- consume: prefetch full W tile slice, wait for block k, apply ----
            float4 wpre[16];
#pragma unroll
            for (int it = 0; it < 16; ++it) {
                const int r = w * 32 + it * 2 + half;
                wpre[it] = *(const float4*)(W + (size_t)(bm + r) * NN + k * BB + 4 * lam);
            }
            int fl;
            do {
                fl = __hip_atomic_load(&flags[e], __ATOMIC_ACQUIRE, __HIP_MEMORY_SCOPE_AGENT);
                if (fl) break;
                __builtin_amdgcn_s_sleep(1);
            } while ((clock64() - tstart) < 1000000000LL);
            if (fl == 1) {
                const float* db = delta_buf + (size_t)e * BB;
                const float4 d4 = *(const float4*)(db + 4 * lam);
#pragma unroll
                for (int it = 0; it < 16; ++it) {
                    const int r = w * 32 + it * 2 + half;
                    const float4 wv = wpre[it];
                    float p = fmaf(wv.x, d4.x, fmaf(wv.y, d4.y, fmaf(wv.z, d4.z, wv.w * d4.w)));
#pragma unroll
                    for (int s = 16; s; s >>= 1) p += __shfl_xor(p, s);
                    if (lam == 0) a_lds[r] += p;   // fixed thread per row: deterministic
                }
            }
        } else {
            // ---- solve my block ----
            __syncthreads();
            if (w == 0) {
                float c0 = a_lds[lane], c1 = a_lds[lane + 64];
                const float dp0 = 1.f - sold0, dm0 = -1.f - sold0;
                const float dp1 = 1.f - sold1, dm1 = -1.f - sold1;
                // speculative all-unchanged check (valid by induction)
                const float cand0 = c0 > 0.f ? dp0 : dm0;
                const float cand1 = c1 > 0.f ? dp1 : dm1;
                const unsigned long long bz = __ballot((cand0 != 0.f) || (cand1 != 0.f));
                float vdf0 = 0.f, vdf1 = 0.f;
                const int zero_all = (bz == 0ULL);
                if (!zero_all) {
                    float vsn0 = sold0, vsn1 = sold1;
                    float pw0[6], pw1[6];
#pragma unroll
                    for (int u = 0; u < 6; ++u) { pw0[u] = wdT[u][lane]; pw1[u] = wdT[u][lane + 64]; }
#pragma unroll
                    for (int j = 0; j < 64; ++j) {      // neurons 0..63 (c0)
                        const float dq = c0 > 0.f ? dp0 : dm0;
                        const float sq = c0 > 0.f ? 1.f : -1.f;
                        const float bc = __int_as_float(
                            __builtin_amdgcn_readlane(__float_as_int(dq), j));
                        const bool me = (lane == j);
                        vdf0 = me ? dq : vdf0;
                        vsn0 = me ? sq : vsn0;
                        const float w0 = pw0[j % 6], w1 = pw1[j % 6];
                        pw0[j % 6] = wdT[j + 6][lane];
                        pw1[j % 6] = wdT[j + 6][lane + 64];
                        c0 = fmaf(w0, bc, c0);
                        c1 = fmaf(w1, bc, c1);
                    }
                    // mid-block speculative skip for second half
                    const float cnd1 = c1 > 0.f ? dp1 : dm1;
                    const unsigned long long bz1 = __ballot(cnd1 != 0.f);
                    if (bz1 != 0ULL) {
#pragma unroll
                        for (int j = 64; j < 128; ++j) {  // neurons 64..127 (c1)
                            const float dq = c1 > 0.f ? dp1 : dm1;
                            const float sq = c1 > 0.f ? 1.f : -1.f;
                            const float bc = __int_as_float(
                                __builtin_amdgcn_readlane(__float_as_int(dq), j & 63));
                            const bool me = (lane == (j & 63));
                            vdf1 = me ? dq : vdf1;
                            vsn1 = me ? sq : vsn1;
                            const float w1 = pw1[j % 6];
                            if (j + 6 < BB) pw1[j % 6] = wdT[j + 6][lane + 64];
                            c1 = fmaf(w1, bc, c1);
                        }
                    }
                    sold0 = vsn0;   // exact ±1 states
                    sold1 = vsn1;
                }
                if (lane == 0) status_lds = zero_all;
                if (!zero_all) {
                    delta_lds[lane] = vdf0;
                    delta_lds[lane + 64] = vdf1;
                    float* db = delta_buf + (size_t)e * BB;
                    db[lane] = vdf0;
                    db[lane + 64] = vdf1;
                }
                __threadfence();
                if (lane == 0)
                    __hip_atomic_store(&flags[e], zero_all ? 2 : 1,
                                       __ATOMIC_RELEASE, __HIP_MEMORY_SCOPE_AGENT);
            }
            __syncthreads();
            // persist intra-block corrections into a_lds (full diag tile @ delta)
            if (!status_lds) {
                float dv[4];
#pragma unroll
                for (int u = 0; u < 4; ++u) dv[u] = delta_lds[lam + 32 * u];
#pragma unroll 2
                for (int it = 0; it < 16; ++it) {
                    const int r = w * 32 + it * 2 + half;
                    float p = 0.f;
#pragma unroll
                    for (int u = 0; u < 4; ++u) p = fmaf(wdT[lam + 32 * u][r], dv[u], p);
#pragma unroll
                    for (int s = 16; s; s >>= 1) p += __shfl_xor(p, s);
                    if (lam == 0) a_lds[r] += p;
                }
            }
        }
    }

    if (w == 0) {
        out[bm + lane] = sold0;
        out[bm + 64 + lane] = sold1;
    }
}

// ---------------------------------------------------------------------------
extern "C" void kernel_launch(void* const* d_in, const int* in_sizes, int n_in,
                              void* d_out, int out_size, void* d_ws, size_t ws_size,
                              hipStream_t stream) {
    const float* x = (const float*)d_in[0];
    const float* W = (const float*)d_in[1];
    const int* maxit = (const int*)d_in[2];
    float* out = (float*)d_out;

    char* ws = (char*)d_ws;
    int* flags = (int*)ws;                                        // 1 KB
    float* delta_buf = (float*)(ws + 1024);                       // 128 KB
    float* partial_buf = (float*)(ws + 1024 + (size_t)MAXE * BB * 4); // 128 KB
    if (ws_size < (size_t)(1024 + 2 * MAXE * BB * 4)) return;     // visible failure

    hipLaunchKernelGGL(hop_init, dim3(256), dim3(256), 0, stream,
                       x, W, flags, partial_buf);

    void* args[7];
    args[0] = (void*)&x; args[1] = (void*)&W; args[2] = (void*)&maxit;
    args[3] = (void*)&out; args[4] = (void*)&flags; args[5] = (void*)&delta_buf;
    args[6] = (void*)&partial_buf;
    (void)hipLaunchCooperativeKernel(hop_main, dim3(GG), dim3(256), args, 0u, stream);
}

// Round 3
// 1103.098 us; speedup vs baseline: 1.0775x; 1.0775x over previous
//
#include <hip/hip_runtime.h>

#define NN 4096
#define BB 128
#define GG 32          // NN / BB
#define MAXT 8
#define MAXE (MAXT * GG)
#define MASK63 0x7FFFFFFFFFFFFFFFull
#define MASK62 0x3FFFFFFFFFFFFFFFull
#define TOPBIT 0x8000000000000000ull

// ---------------------------------------------------------------------------
// Kernel 1: zero mailboxes + parallel partial matvec  a_partial = W @ x
// ---------------------------------------------------------------------------
__global__ __launch_bounds__(256)
void hop_init(const float* __restrict__ x, const float* __restrict__ W,
              unsigned long long* __restrict__ slots, float* __restrict__ partial_buf)
{
    const int tid = threadIdx.x, bid = blockIdx.x;
    const int lane = tid & 63, w = tid >> 6;
    const int lam = lane & 31, half = lane >> 5;

    if (bid == 0) {
        for (int i = tid; i < MAXE * 8; i += 256) slots[i] = 0ull;
    }

    const int tm = bid >> 3, tc = bid & 7;
    const int rbase = tm * BB, cbase = tc * 512;

    float4 xv[4];
#pragma unroll
    for (int u = 0; u < 4; ++u)
        xv[u] = *(const float4*)(x + cbase + 4 * lam + 128 * u);

#pragma unroll 2
    for (int it = 0; it < 16; ++it) {
        const int r = w * 32 + it * 2 + half;
        const float* wrow = W + (size_t)(rbase + r) * NN + cbase;
        float p = 0.f;
#pragma unroll
        for (int u = 0; u < 4; ++u) {
            float4 wv = *(const float4*)(wrow + 4 * lam + 128 * u);
            p = fmaf(wv.x, xv[u].x, p); p = fmaf(wv.y, xv[u].y, p);
            p = fmaf(wv.z, xv[u].z, p); p = fmaf(wv.w, xv[u].w, p);
        }
#pragma unroll
        for (int s = 16; s; s >>= 1) p += __shfl_xor(p, s);
        if (lam == 0) partial_buf[(size_t)bid * BB + r] = p;
    }
}

// ---------------------------------------------------------------------------
// Kernel 2: 32 owner WGs, mailbox-pipelined blocked asynchronous sweeps
// ---------------------------------------------------------------------------
__global__ __launch_bounds__(256)
void hop_main(const float* __restrict__ x, const float* __restrict__ W,
              const int* __restrict__ maxit, float* __restrict__ out,
              unsigned long long* __restrict__ slots,
              const float* __restrict__ partial_buf)
{
    __shared__ float wdT[BB][BB + 1];   // transposed diagonal tile
    __shared__ float a_lds[BB];         // running activations of my block
    __shared__ float prev_lds[NN];      // tracked previous state of ALL blocks
    __shared__ float delta_lds[BB];
    __shared__ int   status_lds;
    __shared__ int   nzw[2][4];         // parity-double-buffered per-wave nz flags

    const int tid = threadIdx.x;
    const int m = blockIdx.x;
    const int lane = tid & 63, w = tid >> 6;
    const int lam = lane & 31, half = lane >> 5;
    const int bm = m * BB;

    int T = *maxit; if (T > MAXT) T = MAXT; if (T < 0) T = 0;
    const long long tstart = clock64();

    // stage transposed diagonal tile
    for (int l = tid; l < BB * BB; l += 256) {
        const int i = l >> 7, j = l & 127;
        wdT[j][i] = W[(size_t)(bm + i) * NN + bm + j];
    }
    // previous-state tracker = initial x
    for (int i = tid; i < NN; i += 256) prev_lds[i] = x[i];
    // gather init matvec partials
    if (tid < BB) {
        float s = 0.f;
#pragma unroll
        for (int c = 0; c < 8; ++c) s += partial_buf[(size_t)(m * 8 + c) * BB + tid];
        a_lds[tid] = s;
    }
    float sold0 = 0.f, sold1 = 0.f;
    if (w == 0) { sold0 = x[bm + lane]; sold1 = x[bm + 64 + lane]; }
    __syncthreads();

    for (int e = 0; e < T * GG; ++e) {
        const int k = e & (GG - 1);
        if (k != m) {
            // ---- consume: prefetch W tile, poll self-validating mailbox ----
            float4 wpre[16];
#pragma unroll
            for (int it = 0; it < 16; ++it) {
                const int r = w * 32 + it * 2 + half;
                wpre[it] = *(const float4*)(W + (size_t)(bm + r) * NN + k * BB + 4 * lam);
            }
            const unsigned long long* sl = slots + (size_t)e * 8;
            unsigned long long q0, q1, q2;
            int iters = 0;
            for (;;) {
                q0 = __hip_atomic_load(&sl[0], __ATOMIC_RELAXED, __HIP_MEMORY_SCOPE_AGENT);
                q1 = __hip_atomic_load(&sl[1], __ATOMIC_RELAXED, __HIP_MEMORY_SCOPE_AGENT);
                q2 = __hip_atomic_load(&sl[2], __ATOMIC_RELAXED, __HIP_MEMORY_SCOPE_AGENT);
                if ((q0 & q1 & q2) >> 63) break;
                __builtin_amdgcn_s_sleep(1);
                if (((++iters) & 255) == 0 && (clock64() - tstart) > 2000000000LL) break;
            }
            const unsigned long long m0 = (q0 & MASK63) | (q1 << 63);
            const unsigned long long m1 = ((q1 >> 1) & MASK62) | (q2 << 62);

            // reconstruct this thread's 4 column-deltas bit-exactly
            const int jc = 4 * lam;
            const float4 pv = *(const float4*)&prev_lds[k * BB + jc];
            float4 d4;
            {
                const float s0 = ((jc + 0 < 64 ? (m0 >> (jc + 0)) : (m1 >> (jc - 64))) & 1) ? 1.f : -1.f;
                const float s1 = ((jc + 1 < 64 ? (m0 >> (jc + 1)) : (m1 >> (jc - 63))) & 1) ? 1.f : -1.f;
                const float s2 = ((jc + 2 < 64 ? (m0 >> (jc + 2)) : (m1 >> (jc - 62))) & 1) ? 1.f : -1.f;
                const float s3 = ((jc + 3 < 64 ? (m0 >> (jc + 3)) : (m1 >> (jc - 61))) & 1) ? 1.f : -1.f;
                d4.x = s0 - pv.x; d4.y = s1 - pv.y; d4.z = s2 - pv.z; d4.w = s3 - pv.w;
            }
            const bool nz = (d4.x != 0.f) || (d4.y != 0.f) || (d4.z != 0.f) || (d4.w != 0.f);
            const unsigned long long bnz = __ballot(nz);
            if (lane == 0) nzw[e & 1][w] = (bnz != 0ull);
            __syncthreads();
            // update tracked previous state for block k
            if (tid < BB) {
                const int b = tid < 64 ? (int)((m0 >> tid) & 1) : (int)((m1 >> (tid - 64)) & 1);
                prev_lds[k * BB + tid] = b ? 1.f : -1.f;
            }
            const int any = nzw[e & 1][0] | nzw[e & 1][1] | nzw[e & 1][2] | nzw[e & 1][3];
            if (any) {
#pragma unroll
                for (int it = 0; it < 16; ++it) {
                    const int r = w * 32 + it * 2 + half;
                    const float4 wv = wpre[it];
                    float p = fmaf(wv.x, d4.x, fmaf(wv.y, d4.y, fmaf(wv.z, d4.z, wv.w * d4.w)));
#pragma unroll
                    for (int s = 16; s; s >>= 1) p += __shfl_xor(p, s);
                    if (lam == 0) a_lds[r] += p;   // fixed thread per row: deterministic
                }
            }
        } else {
            // ---- solve my block ----
            __syncthreads();
            if (w == 0) {
                float c0 = a_lds[lane], c1 = a_lds[lane + 64];
                const float dp0 = 1.f - sold0, dm0 = -1.f - sold0;
                const float dp1 = 1.f - sold1, dm1 = -1.f - sold1;
                const float cand0 = c0 > 0.f ? dp0 : dm0;
                const float cand1 = c1 > 0.f ? dp1 : dm1;
                const unsigned long long bz = __ballot((cand0 != 0.f) || (cand1 != 0.f));
                float vdf0 = 0.f, vdf1 = 0.f;
                const int zero_all = (bz == 0ULL);
                if (!zero_all) {
                    float vsn0 = sold0, vsn1 = sold1;
                    float pw0[6], pw1[6];
#pragma unroll
                    for (int u = 0; u < 6; ++u) { pw0[u] = wdT[u][lane]; pw1[u] = wdT[u][lane + 64]; }
#pragma unroll
                    for (int j = 0; j < 64; ++j) {      // neurons 0..63 (c0)
                        const float dq = c0 > 0.f ? dp0 : dm0;
                        const float sq = c0 > 0.f ? 1.f : -1.f;
                        const float bc = __int_as_float(
                            __builtin_amdgcn_readlane(__float_as_int(dq), j));
                        const bool me = (lane == j);
                        vdf0 = me ? dq : vdf0;
                        vsn0 = me ? sq : vsn0;
                        const float w0 = pw0[j % 6], w1 = pw1[j % 6];
                        pw0[j % 6] = wdT[j + 6][lane];
                        pw1[j % 6] = wdT[j + 6][lane + 64];
                        c0 = fmaf(w0, bc, c0);
                        c1 = fmaf(w1, bc, c1);
                    }
                    const float cnd1 = c1 > 0.f ? dp1 : dm1;
                    const unsigned long long bz1 = __ballot(cnd1 != 0.f);
                    if (bz1 != 0ULL) {
#pragma unroll
                        for (int j = 64; j < 128; ++j) {  // neurons 64..127 (c1)
                            const float dq = c1 > 0.f ? dp1 : dm1;
                            const float sq = c1 > 0.f ? 1.f : -1.f;
                            const float bc = __int_as_float(
                                __builtin_amdgcn_readlane(__float_as_int(dq), j & 63));
                            const bool me = (lane == (j & 63));
                            vdf1 = me ? dq : vdf1;
                            vsn1 = me ? sq : vsn1;
                            const float w1 = pw1[j % 6];
                            if (j + 6 < BB) pw1[j % 6] = wdT[j + 6][lane + 64];
                            c1 = fmaf(w1, bc, c1);
                        }
                    }
                    sold0 = vsn0;
                    sold1 = vsn1;
                }
                // ---- publish IMMEDIATELY: 3 self-validating relaxed stores ----
                {
                    const unsigned long long m0 = __ballot(sold0 > 0.f);
                    const unsigned long long m1 = __ballot(sold1 > 0.f);
                    unsigned long long* sl = slots + (size_t)e * 8;
                    if (lane == 0) {
                        __hip_atomic_store(&sl[0], TOPBIT | (m0 & MASK63),
                                           __ATOMIC_RELAXED, __HIP_MEMORY_SCOPE_AGENT);
                        __hip_atomic_store(&sl[1], TOPBIT | (m0 >> 63) | ((m1 & MASK62) << 1),
                                           __ATOMIC_RELAXED, __HIP_MEMORY_SCOPE_AGENT);
                        __hip_atomic_store(&sl[2], TOPBIT | (m1 >> 62),
                                           __ATOMIC_RELAXED, __HIP_MEMORY_SCOPE_AGENT);
                    }
                }
                if (lane == 0) status_lds = zero_all;
                if (!zero_all) {
                    delta_lds[lane] = vdf0;
                    delta_lds[lane + 64] = vdf1;
                }
            }
            __syncthreads();
            // persist intra-block corrections into a_lds
            if (!status_lds) {
                float dv[4];
#pragma unroll
                for (int u = 0; u < 4; ++u) dv[u] = delta_lds[lam + 32 * u];
#pragma unroll 2
                for (int it = 0; it < 16; ++it) {
                    const int r = w * 32 + it * 2 + half;
                    float p = 0.f;
#pragma unroll
                    for (int u = 0; u < 4; ++u) p = fmaf(wdT[lam + 32 * u][r], dv[u], p);
#pragma unroll
                    for (int s = 16; s; s >>= 1) p += __shfl_xor(p, s);
                    if (lam == 0) a_lds[r] += p;
                }
            }
        }
    }

    if (w == 0) {
        out[bm + lane] = sold0;
        out[bm + 64 + lane] = sold1;
    }
}

// ---------------------------------------------------------------------------
extern "C" void kernel_launch(void* const* d_in, const int* in_sizes, int n_in,
                              void* d_out, int out_size, void* d_ws, size_t ws_size,
                              hipStream_t stream) {
    const float* x = (const float*)d_in[0];
    const float* W = (const float*)d_in[1];
    const int* maxit = (const int*)d_in[2];
    float* out = (float*)d_out;

    char* ws = (char*)d_ws;
    unsigned long long* slots = (unsigned long long*)ws;              // 16 KB
    float* partial_buf = (float*)(ws + (size_t)MAXE * 8 * 8);         // 128 KB
    if (ws_size < (size_t)(MAXE * 64 + 256 * BB * 4)) return;

    hipLaunchKernelGGL(hop_init, dim3(256), dim3(256), 0, stream,
                       x, W, slots, partial_buf);

    void* args[6];
    args[0] = (void*)&x; args[1] = (void*)&W; args[2] = (void*)&maxit;
    args[3] = (void*)&out; args[4] = (void*)&slots; args[5] = (void*)&partial_buf;
    (void)hipLaunchCooperativeKernel(hop_main, dim3(GG), dim3(256), args, 0u, stream);
}

// Round 4
// 1060.355 us; speedup vs baseline: 1.1209x; 1.0403x over previous
//
#include <hip/hip_runtime.h>

#define NN 4096
#define BB 128
#define GG 32          // NN / BB
#define MAXT 8
#define MAXE (MAXT * GG)
#define MASK63 0x7FFFFFFFFFFFFFFFull
#define MASK62 0x3FFFFFFFFFFFFFFFull
#define TOPBIT 0x8000000000000000ull

// ---------------------------------------------------------------------------
// Kernel 1: zero mailboxes + parallel partial matvec  a_partial = W @ x
// ---------------------------------------------------------------------------
__global__ __launch_bounds__(256)
void hop_init(const float* __restrict__ x, const float* __restrict__ W,
              unsigned long long* __restrict__ slots, float* __restrict__ partial_buf)
{
    const int tid = threadIdx.x, bid = blockIdx.x;
    const int lane = tid & 63, w = tid >> 6;
    const int lam = lane & 31, half = lane >> 5;

    if (bid == 0) {
        for (int i = tid; i < MAXE * 8; i += 256) slots[i] = 0ull;
    }

    const int tm = bid >> 3, tc = bid & 7;
    const int rbase = tm * BB, cbase = tc * 512;

    float4 xv[4];
#pragma unroll
    for (int u = 0; u < 4; ++u)
        xv[u] = *(const float4*)(x + cbase + 4 * lam + 128 * u);

#pragma unroll 2
    for (int it = 0; it < 16; ++it) {
        const int r = w * 32 + it * 2 + half;
        const float* wrow = W + (size_t)(rbase + r) * NN + cbase;
        float p = 0.f;
#pragma unroll
        for (int u = 0; u < 4; ++u) {
            float4 wv = *(const float4*)(wrow + 4 * lam + 128 * u);
            p = fmaf(wv.x, xv[u].x, p); p = fmaf(wv.y, xv[u].y, p);
            p = fmaf(wv.z, xv[u].z, p); p = fmaf(wv.w, xv[u].w, p);
        }
#pragma unroll
        for (int s = 16; s; s >>= 1) p += __shfl_xor(p, s);
        if (lam == 0) partial_buf[(size_t)bid * BB + r] = p;
    }
}

// ---------------------------------------------------------------------------
// Kernel 2: 32 owner WGs, mailbox-pipelined blocked asynchronous sweeps
// Wave 0 is the sole poller; distance-aware backoff kills mailbox contention.
// ---------------------------------------------------------------------------
__global__ __launch_bounds__(256)
void hop_main(const float* __restrict__ x, const float* __restrict__ W,
              const int* __restrict__ maxit, float* __restrict__ out,
              unsigned long long* __restrict__ slots,
              const float* __restrict__ partial_buf)
{
    __shared__ float wdT[BB][BB + 1];          // transposed diagonal tile
    __shared__ float pbuf[2][NN];              // prev-state tracker, sweep parity
    __shared__ float a_lds[BB];                // running activations of my block
    __shared__ float delta_lds[BB];
    __shared__ unsigned long long mbox[2][2];  // stage-parity mask broadcast
    __shared__ unsigned long long pm[2][GG][2];// last published mask per block
    __shared__ int   status_lds;

    const int tid = threadIdx.x;
    const int m = blockIdx.x;
    const int lane = tid & 63, w = tid >> 6;
    const int lam = lane & 31, half = lane >> 5;
    const int bm = m * BB;

    int T = *maxit; if (T > MAXT) T = MAXT; if (T < 0) T = 0;
    const long long tstart = clock64();

    // stage transposed diagonal tile
    for (int l = tid; l < BB * BB; l += 256) {
        const int i = l >> 7, j = l & 127;
        wdT[j][i] = W[(size_t)(bm + i) * NN + bm + j];
    }
    // previous-state tracker (sweep-0 buffer) = initial x
    for (int i = tid; i < NN; i += 256) pbuf[0][i] = x[i];
    // gather init matvec partials
    if (tid < BB) {
        float s = 0.f;
#pragma unroll
        for (int c = 0; c < 8; ++c) s += partial_buf[(size_t)(m * 8 + c) * BB + tid];
        a_lds[tid] = s;
    }
    float sold0 = 0.f, sold1 = 0.f;
    if (w == 0) { sold0 = x[bm + lane]; sold1 = x[bm + 64 + lane]; }
    __syncthreads();

    for (int e = 0; e < T * GG; ++e) {
        const int k = e & (GG - 1);
        const int s = e >> 5;                   // sweep index
        if (k != m) {
            // ---- consume: prefetch W tile; wave 0 polls; broadcast via LDS ----
            float4 wpre[16];
#pragma unroll
            for (int it = 0; it < 16; ++it) {
                const int r = w * 32 + it * 2 + half;
                wpre[it] = *(const float4*)(W + (size_t)(bm + r) * NN + k * BB + 4 * lam);
            }
            if (w == 0) {
                const unsigned long long* sl = slots + (size_t)e * 8;
                const int dist = (m - k + GG) & (GG - 1);   // stages until my solve
                unsigned long long q0, q1, q2;
                long long iters = 0;
                for (;;) {
                    q0 = __hip_atomic_load(&sl[0], __ATOMIC_RELAXED, __HIP_MEMORY_SCOPE_AGENT);
                    q1 = __hip_atomic_load(&sl[1], __ATOMIC_RELAXED, __HIP_MEMORY_SCOPE_AGENT);
                    q2 = __hip_atomic_load(&sl[2], __ATOMIC_RELAXED, __HIP_MEMORY_SCOPE_AGENT);
                    if ((q0 & q1 & q2) >> 63) break;
                    if (dist == 1)      __builtin_amdgcn_s_sleep(1);
                    else if (dist <= 4) __builtin_amdgcn_s_sleep(4);
                    else                __builtin_amdgcn_s_sleep(32);
                    if (((++iters) & 63) == 0 && (clock64() - tstart) > 500000000LL) break;
                }
                const unsigned long long mm0 = (q0 & MASK63) | (q1 << 63);
                const unsigned long long mm1 = ((q1 >> 1) & MASK62) | (q2 << 62);
                if (lane == 0) {
                    mbox[e & 1][0] = mm0;
                    mbox[e & 1][1] = mm1;
                    pm[s & 1][k][0] = mm0;       // for next sweep's change test
                    pm[s & 1][k][1] = mm1;
                }
            }
            __syncthreads();
            const unsigned long long m0 = mbox[e & 1][0];
            const unsigned long long m1 = mbox[e & 1][1];
            // uniform "block changed?" test vs previous sweep's published mask
            const bool any = (s == 0) ||
                             (m0 != pm[(s - 1) & 1][k][0]) ||
                             (m1 != pm[(s - 1) & 1][k][1]);

            // reconstruct this thread's 4 column-deltas bit-exactly
            const int jc = 4 * lam;
            const float4 pv = *(const float4*)&pbuf[s & 1][k * BB + jc];
            float4 d4;
            {
                const float s0 = ((jc + 0 < 64 ? (m0 >> (jc + 0)) : (m1 >> (jc - 64))) & 1) ? 1.f : -1.f;
                const float s1 = ((jc + 1 < 64 ? (m0 >> (jc + 1)) : (m1 >> (jc - 63))) & 1) ? 1.f : -1.f;
                const float s2 = ((jc + 2 < 64 ? (m0 >> (jc + 2)) : (m1 >> (jc - 62))) & 1) ? 1.f : -1.f;
                const float s3 = ((jc + 3 < 64 ? (m0 >> (jc + 3)) : (m1 >> (jc - 61))) & 1) ? 1.f : -1.f;
                d4.x = s0 - pv.x; d4.y = s1 - pv.y; d4.z = s2 - pv.z; d4.w = s3 - pv.w;
            }
            // carry tracked state into next sweep's buffer
            if (tid < BB) {
                const int b = tid < 64 ? (int)((m0 >> tid) & 1) : (int)((m1 >> (tid - 64)) & 1);
                pbuf[(s + 1) & 1][k * BB + tid] = b ? 1.f : -1.f;
            }
            if (any) {
#pragma unroll
                for (int it = 0; it < 16; ++it) {
                    const int r = w * 32 + it * 2 + half;
                    const float4 wv = wpre[it];
                    float p = fmaf(wv.x, d4.x, fmaf(wv.y, d4.y, fmaf(wv.z, d4.z, wv.w * d4.w)));
#pragma unroll
                    for (int sh = 16; sh; sh >>= 1) p += __shfl_xor(p, sh);
                    if (lam == 0) a_lds[r] += p;   // fixed thread per row: deterministic
                }
            }
        } else {
            // ---- solve my block ----
            __syncthreads();
            if (w == 0) {
                float c0 = a_lds[lane], c1 = a_lds[lane + 64];
                const float dp0 = 1.f - sold0, dm0 = -1.f - sold0;
                const float dp1 = 1.f - sold1, dm1 = -1.f - sold1;
                const float cand0 = c0 > 0.f ? dp0 : dm0;
                const float cand1 = c1 > 0.f ? dp1 : dm1;
                const unsigned long long bz = __ballot((cand0 != 0.f) || (cand1 != 0.f));
                float vdf0 = 0.f, vdf1 = 0.f;
                const int zero_all = (bz == 0ULL);
                if (!zero_all) {
                    float vsn0 = sold0, vsn1 = sold1;
                    float pw0[6], pw1[6];
#pragma unroll
                    for (int u = 0; u < 6; ++u) { pw0[u] = wdT[u][lane]; pw1[u] = wdT[u][lane + 64]; }
#pragma unroll
                    for (int j = 0; j < 64; ++j) {      // neurons 0..63 (c0)
                        const float dq = c0 > 0.f ? dp0 : dm0;
                        const float sq = c0 > 0.f ? 1.f : -1.f;
                        const float bc = __int_as_float(
                            __builtin_amdgcn_readlane(__float_as_int(dq), j));
                        const bool me = (lane == j);
                        vdf0 = me ? dq : vdf0;
                        vsn0 = me ? sq : vsn0;
                        const float w0 = pw0[j % 6], w1 = pw1[j % 6];
                        pw0[j % 6] = wdT[j + 6][lane];
                        pw1[j % 6] = wdT[j + 6][lane + 64];
                        c0 = fmaf(w0, bc, c0);
                        c1 = fmaf(w1, bc, c1);
                    }
                    const float cnd1 = c1 > 0.f ? dp1 : dm1;
                    const unsigned long long bz1 = __ballot(cnd1 != 0.f);
                    if (bz1 != 0ULL) {
#pragma unroll
                        for (int j = 64; j < 128; ++j) {  // neurons 64..127 (c1)
                            const float dq = c1 > 0.f ? dp1 : dm1;
                            const float sq = c1 > 0.f ? 1.f : -1.f;
                            const float bc = __int_as_float(
                                __builtin_amdgcn_readlane(__float_as_int(dq), j & 63));
                            const bool me = (lane == (j & 63));
                            vdf1 = me ? dq : vdf1;
                            vsn1 = me ? sq : vsn1;
                            const float w1 = pw1[j % 6];
                            if (j + 6 < BB) pw1[j % 6] = wdT[j + 6][lane + 64];
                            c1 = fmaf(w1, bc, c1);
                        }
                    }
                    sold0 = vsn0;
                    sold1 = vsn1;
                }
                // ---- publish IMMEDIATELY: 3 self-validating relaxed stores ----
                {
                    const unsigned long long pm0 = __ballot(sold0 > 0.f);
                    const unsigned long long pm1 = __ballot(sold1 > 0.f);
                    unsigned long long* sl = slots + (size_t)e * 8;
                    if (lane == 0) {
                        __hip_atomic_store(&sl[0], TOPBIT | (pm0 & MASK63),
                                           __ATOMIC_RELAXED, __HIP_MEMORY_SCOPE_AGENT);
                        __hip_atomic_store(&sl[1], TOPBIT | (pm0 >> 63) | ((pm1 & MASK62) << 1),
                                           __ATOMIC_RELAXED, __HIP_MEMORY_SCOPE_AGENT);
                        __hip_atomic_store(&sl[2], TOPBIT | (pm1 >> 62),
                                           __ATOMIC_RELAXED, __HIP_MEMORY_SCOPE_AGENT);
                    }
                }
                if (lane == 0) status_lds = zero_all;
                if (!zero_all) {
                    delta_lds[lane] = vdf0;
                    delta_lds[lane + 64] = vdf1;
                }
            }
            __syncthreads();
            // persist intra-block corrections into a_lds
            if (!status_lds) {
                float dv[4];
#pragma unroll
                for (int u = 0; u < 4; ++u) dv[u] = delta_lds[lam + 32 * u];
#pragma unroll 2
                for (int it = 0; it < 16; ++it) {
                    const int r = w * 32 + it * 2 + half;
                    float p = 0.f;
#pragma unroll
                    for (int u = 0; u < 4; ++u) p = fmaf(wdT[lam + 32 * u][r], dv[u], p);
#pragma unroll
                    for (int sh = 16; sh; sh >>= 1) p += __shfl_xor(p, sh);
                    if (lam == 0) a_lds[r] += p;
                }
            }
        }
    }

    if (w == 0) {
        out[bm + lane] = sold0;
        out[bm + 64 + lane] = sold1;
    }
}

// ---------------------------------------------------------------------------
extern "C" void kernel_launch(void* const* d_in, const int* in_sizes, int n_in,
                              void* d_out, int out_size, void* d_ws, size_t ws_size,
                              hipStream_t stream) {
    const float* x = (const float*)d_in[0];
    const float* W = (const float*)d_in[1];
    const int* maxit = (const int*)d_in[2];
    float* out = (float*)d_out;

    char* ws = (char*)d_ws;
    unsigned long long* slots = (unsigned long long*)ws;              // 16 KB
    float* partial_buf = (float*)(ws + (size_t)MAXE * 8 * 8);         // 128 KB
    if (ws_size < (size_t)(MAXE * 64 + 256 * BB * 4)) return;

    hipLaunchKernelGGL(hop_init, dim3(256), dim3(256), 0, stream,
                       x, W, slots, partial_buf);

    void* args[6];
    args[0] = (void*)&x; args[1] = (void*)&W; args[2] = (void*)&maxit;
    args[3] = (void*)&out; args[4] = (void*)&slots; args[5] = (void*)&partial_buf;
    (void)hipLaunchCooperativeKernel(hop_main, dim3(GG), dim3(256), args, 0u, stream);
}